// Round 2
// baseline (2770.190 us; speedup 1.0000x reference)
//
#include <hip/hip_runtime.h>
#include <hip/hip_bf16.h>

// Bidirectional LSTM, B=32 T=512 D=512 U=512, fp32 in/out, bf16 MFMA internals.
// Phase 1: xg = x @ [Wf||Wb] + b  (bf16 MFMA GEMM, permuted columns)
// Phase 2: persistent recurrence, 32 groups/direction, U^T in registers.
//          R6b: h exchange as 8B {bf16 h0, bf16 h1, u32 step} records meeting at
//          Infinity Cache. Data IS the flag: one round trip per step (poll load
//          returns the payload), fire-and-forget publish, lgkm-only barriers
//          (no vmcnt drain on the critical path), no mailboxes.
// Phase 3: out = fwd + bwd

typedef __attribute__((ext_vector_type(8))) __bf16 bf16x8;
typedef __attribute__((ext_vector_type(4))) __bf16 bf16x4;
typedef __attribute__((ext_vector_type(4))) float fvec4;
typedef __attribute__((ext_vector_type(2))) float fvec2;

#define AS_G(p) ((const __attribute__((address_space(1))) void*)(p))
#define AS_L(p) ((__attribute__((address_space(3))) void*)(p))

__device__ __forceinline__ float sigm(float x) {
  return __builtin_amdgcn_rcpf(1.f + __expf(-x));
}
__device__ __forceinline__ float tanh_f(float x) {
  return 1.f - 2.f * __builtin_amdgcn_rcpf(__expf(2.f * x) + 1.f);
}

// ---------------- conversions ----------------

__global__ void k_convert_x(const float* __restrict__ x, __bf16* __restrict__ xb) {
  size_t i = ((size_t)blockIdx.x * 256 + threadIdx.x) * 8;
  fvec4 a = *(const fvec4*)(x + i);
  fvec4 b = *(const fvec4*)(x + i + 4);
  bf16x8 o;
#pragma unroll
  for (int j = 0; j < 4; ++j) { o[j] = (__bf16)a[j]; o[4 + j] = (__bf16)b[j]; }
  *(bf16x8*)(xb + i) = o;
}

// dst[p][k] = src[k][orig(p)] as bf16. Permutation: p = g*64 + w*16 + jj*4 + gate
// <-> orig = gate*512 + g*16 + w*4 + jj  (Keras gate order i,f,c,o).
__global__ void k_build_T(const float* __restrict__ src, const float* __restrict__ bvec,
                          __bf16* __restrict__ dst, float* __restrict__ bias_out) {
  int p = blockIdx.x;
  int g = p >> 6, r = p & 63, w = r >> 4, q = r & 15, jj = q >> 2, gate = q & 3;
  int orig = gate * 512 + g * 16 + w * 4 + jj;
  for (int k = threadIdx.x; k < 512; k += 256)
    dst[(size_t)p * 512 + k] = (__bf16)src[(size_t)k * 2048 + orig];
  if (bias_out && threadIdx.x == 0) bias_out[p] = bvec[orig];
}

// init h records: [dir 2][par 2][ks 16][row 32][cp 16] of 8B {h pair, step}.
// parity 0 holds h(0)=z with step counter 0; parity 1 zeroed (counter 0 never
// matches an odd step, so consumers of step 1 wait for the real publish).
__global__ void k_init_rec(const float* __restrict__ z,
                           unsigned long long* __restrict__ rbuf) {
  int idx = blockIdx.x * 256 + threadIdx.x;      // 0..32767
  int par = (idx >> 13) & 1;
  int ks = (idx >> 9) & 15, row = (idx >> 4) & 31, cp = idx & 15;
  unsigned long long v = 0ull;
  if (par == 0) {
    union { __bf16 h[2]; unsigned u; } pk;
    pk.h[0] = (__bf16)z[row * 512 + ks * 32 + cp * 2];
    pk.h[1] = (__bf16)z[row * 512 + ks * 32 + cp * 2 + 1];
    v = (unsigned long long)pk.u;                // counter 0 in high word
  }
  rbuf[idx] = v;
}

// ---------------- input GEMM: [16384,512] x [4096,512]^T -> bf16 [16384,4096] ----------------

__global__ __launch_bounds__(256, 2) void k_gemm_xw(
    const __bf16* __restrict__ A,   // [16384][512] bf16
    const __bf16* __restrict__ Bt,  // [4096][512] bf16 (permuted W^T)
    const float* __restrict__ bias, // [4096] permuted
    __bf16* __restrict__ C)         // [16384][4096]
{
  __shared__ __align__(16) __bf16 As[128 * 32];
  __shared__ __align__(16) __bf16 Bs[128 * 32];
  const int tid = threadIdx.x;
  const int w = tid >> 6, lane = tid & 63, quad = lane >> 4, l15 = lane & 15;
  const int m0 = blockIdx.y * 128, n0 = blockIdx.x * 128;
  const int wm = w & 1, wn = w >> 1;

  fvec4 acc[4][4];
  const fvec4 zero = {0.f, 0.f, 0.f, 0.f};
#pragma unroll
  for (int i = 0; i < 4; ++i)
#pragma unroll
    for (int j = 0; j < 4; ++j) acc[i][j] = zero;

  for (int kb = 0; kb < 16; ++kb) {
    const int k0 = kb * 32;
#pragma unroll
    for (int i = 0; i < 2; ++i) {
      const int c = (i * 4 + w) * 64 + lane;      // 16B chunk id, 0..511
      const int row = c >> 2, kk = (c & 3) * 8;
      __builtin_amdgcn_global_load_lds(AS_G(A + (size_t)(m0 + row) * 512 + k0 + kk),
                                       AS_L(As + (size_t)(i * 4 + w) * 512), 16, 0, 0);
      __builtin_amdgcn_global_load_lds(AS_G(Bt + (size_t)(n0 + row) * 512 + k0 + kk),
                                       AS_L(Bs + (size_t)(i * 4 + w) * 512), 16, 0, 0);
    }
    __syncthreads();
    bf16x8 af[4], bfr[4];
#pragma unroll
    for (int mt = 0; mt < 4; ++mt)
      af[mt] = *(const bf16x8*)(As + (wm * 64 + mt * 16 + l15) * 32 + quad * 8);
#pragma unroll
    for (int nt = 0; nt < 4; ++nt)
      bfr[nt] = *(const bf16x8*)(Bs + (wn * 64 + nt * 16 + l15) * 32 + quad * 8);
#pragma unroll
    for (int mt = 0; mt < 4; ++mt)
#pragma unroll
      for (int nt = 0; nt < 4; ++nt)
        acc[mt][nt] = __builtin_amdgcn_mfma_f32_16x16x32_bf16(af[mt], bfr[nt], acc[mt][nt], 0, 0, 0);
    __syncthreads();
  }

#pragma unroll
  for (int nt = 0; nt < 4; ++nt) {
    const int col = n0 + wn * 64 + nt * 16 + l15;
    const float bv = bias[col];
#pragma unroll
    for (int mt = 0; mt < 4; ++mt) {
      const int rowb = m0 + wm * 64 + mt * 16 + quad * 4;
#pragma unroll
      for (int r = 0; r < 4; ++r)
        C[(size_t)(rowb + r) * 4096 + col] = (__bf16)(acc[mt][nt][r] + bv);
    }
  }
}

// ---------------- persistent recurrence ----------------
// 64 blocks: dir = blk>>5, group g = blk&31 owns h-cols [g*16, g*16+16).
// rbuf (global): [2 dir][2 parity][16 ks][32 row][16 cp] u64 records
//   {low 4B: 2x bf16 h, high 4B: step}. One 8B store = single-copy atomic,
//   so the step counter certifies the payload — no separate flags, no drains.
// Poll safety: producer P publishes kt+1 only after P's step-kt poll passed,
//   which requires all 8192 step-kt records, which requires every block to
//   have passed barrier (B) of iteration kt-1, which requires every staging
//   load of the step-(kt-1) records (the ones P overwrites) to have returned.
//   So '== kt' matches exactly the wanted generation; no lost updates.
// h_lds: [ks][row 32][cp 16] 4B payloads, ks-stride 2080B (8-bank rotation):
//   staging b32 writes = exact 2-way (free); fragment ds_read_b128 covers all
//   32 banks evenly (structural minimum).

__global__ __launch_bounds__(256, 1) void k_lstm_rec(
    const __bf16* __restrict__ xg,            // [16384][4096] permuted
    const float* __restrict__ z,              // [32][512]
    const __bf16* __restrict__ UT,            // [2][2048][512] permuted
    unsigned long long* __restrict__ rbuf,    // [2][2][8192] records
    float* __restrict__ outf,                 // d_out [32][512][512] (fwd)
    __bf16* __restrict__ outb)                // ws [32][512][512] (bwd)
{
  const int blk = blockIdx.x, dir = blk >> 5, g = blk & 31;
  const int tid = threadIdx.x, w = tid >> 6, lane = tid & 63;
  const int quad = lane >> 4, l15 = lane & 15;
  __shared__ __align__(16) char h_lds[16 * 2080];   // 33.3 KB
  __shared__ __align__(16) float gates[32][68];

  // U^T slice resident in registers for all 512 steps (64 VGPRs)
  bf16x8 breg[16];
  {
    const __bf16* up = UT + ((size_t)dir * 2048 + g * 64 + w * 16 + l15) * 512 + quad * 8;
#pragma unroll
    for (int ks = 0; ks < 16; ++ks) breg[ks] = *(const bf16x8*)(up + ks * 32);
  }

  const int b = lane >> 1, jpair = lane & 1;
  const int hcol = g * 16 + w * 4 + jpair * 2;
  float c0 = z[b * 512 + hcol];
  float c1 = z[b * 512 + hcol + 1];

  // staging role: thread (ks_s = tid>>4, cp = tid&15) owns records [ks_s][*][cp]
  // (all 32 rows of one colpair — written by exactly ONE producer wave, so
  //  freshness flips all-or-nothing per thread).
  const int ks_s = tid >> 4, cp = tid & 15;
  unsigned long long* rb_dir = rbuf + (size_t)dir * 16384;
  unsigned long long* src_base = rb_dir + ks_s * 512 + cp;
  // producer record index: ks = g>>1, row = b, cp = (g&1)*8 + w*2 + jpair
  const int pidx = (g >> 1) * 512 + b * 16 + (g & 1) * 8 + w * 2 + jpair;

  for (int kt = 0; kt < 512; ++kt) {
    const int t = dir ? (511 - kt) : kt;
    const int pr = kt & 1;

    // (A) all waves done reading h_lds of step kt-1. LDS-only drain: publish/out
    // stores stay in flight; their acks overlap the poll's vmcnt(0) below.
    asm volatile("s_waitcnt lgkmcnt(0)\n\ts_barrier" ::: "memory");

    // xg prefetch (completes under the poll)
    const bf16x8 xv = *(const bf16x8*)(xg + (size_t)(b * 512 + t) * 4096 +
                                       dir * 2048 + g * 64 + w * 16 + jpair * 8);

    // ---- poll-on-data staging: 32 x 8B records, 128B stride, imm offsets ----
    unsigned long long rec[32];
    {
      unsigned long long* srcp = src_base + pr * 8192;
      const unsigned expect = (unsigned)kt;
      for (;;) {
#pragma unroll
        for (int it = 0; it < 32; ++it)
          rec[it] = __hip_atomic_load(srcp + it * 16, __ATOMIC_RELAXED,
                                      __HIP_MEMORY_SCOPE_AGENT);
        // wait all 32 loads; also retires older stores (kills same-address WAW)
        asm volatile("s_waitcnt vmcnt(0)" ::: "memory");
        unsigned ok = 1u;
#pragma unroll
        for (int it = 0; it < 32; ++it)
          ok &= (unsigned)((unsigned)(rec[it] >> 32) == expect);
        if (__all((int)ok)) break;
        __builtin_amdgcn_s_sleep(1);
      }
    }
#pragma unroll
    for (int it = 0; it < 32; ++it)
      *(unsigned*)(h_lds + ks_s * 2080 + it * 64 + cp * 4) = (unsigned)rec[it];

    // (B) staging visible to all waves
    asm volatile("s_waitcnt lgkmcnt(0)\n\ts_barrier" ::: "memory");

    fvec4 acc0 = {0.f, 0.f, 0.f, 0.f}, acc1 = {0.f, 0.f, 0.f, 0.f};
#pragma unroll 8
    for (int ks = 0; ks < 16; ++ks) {
      bf16x8 a0 = *(const bf16x8*)(h_lds + ks * 2080 + l15 * 64 + quad * 16);
      bf16x8 a1 = *(const bf16x8*)(h_lds + ks * 2080 + 1024 + l15 * 64 + quad * 16);
      acc0 = __builtin_amdgcn_mfma_f32_16x16x32_bf16(a0, breg[ks], acc0, 0, 0, 0);
      acc1 = __builtin_amdgcn_mfma_f32_16x16x32_bf16(a1, breg[ks], acc1, 0, 0, 0);
    }

    // transpose gates within the wave's private LDS columns
#pragma unroll
    for (int r = 0; r < 4; ++r) {
      gates[quad * 4 + r][w * 16 + l15] = acc0[r];
      gates[16 + quad * 4 + r][w * 16 + l15] = acc1[r];
    }
    const fvec4 gA = *(const fvec4*)&gates[b][w * 16 + jpair * 8];
    const fvec4 gB = *(const fvec4*)&gates[b][w * 16 + jpair * 8 + 4];

    float xf[8];
#pragma unroll
    for (int j = 0; j < 8; ++j) xf[j] = (float)xv[j];

    float ii = sigm(gA[0] + xf[0]);
    float ff = sigm(gA[1] + xf[1]);
    float cc = tanh_f(gA[2] + xf[2]);
    float oo = sigm(gA[3] + xf[3]);
    c0 = ff * c0 + ii * cc;
    const float h0 = oo * tanh_f(c0);

    ii = sigm(gB[0] + xf[4]);
    ff = sigm(gB[1] + xf[5]);
    cc = tanh_f(gB[2] + xf[6]);
    oo = sigm(gB[3] + xf[7]);
    c1 = ff * c1 + ii * cc;
    const float h1 = oo * tanh_f(c1);

    // fire-and-forget publish: {h0,h1,kt+1} in one single-copy-atomic 8B record
    union { __bf16 h[2]; unsigned u; } pk;
    pk.h[0] = (__bf16)h0;
    pk.h[1] = (__bf16)h1;
    const unsigned long long rv =
        (unsigned long long)pk.u | ((unsigned long long)(unsigned)(kt + 1) << 32);
    __hip_atomic_store(rb_dir + ((kt + 1) & 1) * 8192 + pidx, rv,
                       __ATOMIC_RELAXED, __HIP_MEMORY_SCOPE_AGENT);

    // out stores off the critical path (drain overlaps future polls / kernel end)
    const size_t oidx = (size_t)(b * 512 + t) * 512 + hcol;
    if (dir == 0) {
      fvec2 ov = {h0, h1};
      *(fvec2*)(outf + oidx) = ov;
    } else {
      *(unsigned*)(outb + oidx) = pk.u;   // same packed bf16 pair
    }
  }
}

// ---------------- final merge ----------------

__global__ void k_add_bwd(float* __restrict__ out, const __bf16* __restrict__ outb) {
  size_t i = ((size_t)blockIdx.x * 256 + threadIdx.x) * 4;
  if (i >= (size_t)32 * 512 * 512) return;
  fvec4 o = *(const fvec4*)(out + i);
  bf16x4 bv = *(const bf16x4*)(outb + i);
#pragma unroll
  for (int j = 0; j < 4; ++j) o[j] += (float)bv[j];
  *(fvec4*)(out + i) = o;
}

// ---------------- host ----------------

extern "C" void kernel_launch(void* const* d_in, const int* in_sizes, int n_in,
                              void* d_out, int out_size, void* d_ws, size_t ws_size,
                              hipStream_t stream) {
  const float* x  = (const float*)d_in[0];
  const float* z  = (const float*)d_in[1];
  const float* Wf = (const float*)d_in[2];
  const float* Uf = (const float*)d_in[3];
  const float* bf = (const float*)d_in[4];
  const float* Wb = (const float*)d_in[5];
  const float* Ub = (const float*)d_in[6];
  const float* bb = (const float*)d_in[7];
  float* out = (float*)d_out;
  char* ws = (char*)d_ws;

  size_t off = 0;
  __bf16* xg = (__bf16*)(ws + off); off += (size_t)16384 * 4096 * 2;   // 134 MB
  __bf16* UT = (__bf16*)(ws + off); off += (size_t)2 * 2048 * 512 * 2; // 4 MB
  unsigned long long* rbuf = (unsigned long long*)(ws + off);
  off += (size_t)2 * 2 * 8192 * 8;                                     // 256 KB
  float* biasp = (float*)(ws + off); off += 4096 * 4;
  char* uni = ws + off;
  __bf16* xb   = (__bf16*)uni;                               // phase 1
  __bf16* WT   = (__bf16*)(uni + (size_t)16384 * 512 * 2);   // phase 1
  __bf16* outb = (__bf16*)uni;                               // phase 2 (aliases xb)

  k_convert_x<<<4096, 256, 0, stream>>>(x, xb);
  k_build_T<<<2048, 256, 0, stream>>>(Wf, bf, WT, biasp);
  k_build_T<<<2048, 256, 0, stream>>>(Wb, bb, WT + (size_t)2048 * 512, biasp + 2048);
  k_build_T<<<2048, 256, 0, stream>>>(Uf, nullptr, UT, nullptr);
  k_build_T<<<2048, 256, 0, stream>>>(Ub, nullptr, UT + (size_t)2048 * 512, nullptr);
  k_init_rec<<<128, 256, 0, stream>>>(z, rbuf);
  k_gemm_xw<<<dim3(32, 128), 256, 0, stream>>>(xb, WT, biasp, xg);
  k_lstm_rec<<<64, 256, 0, stream>>>(xg, z, UT, rbuf, out, outb);
  k_add_bwd<<<8192, 256, 0, stream>>>(out, outb);
}